// Round 1
// baseline (5352.385 us; speedup 1.0000x reference)
//
#include <hip/hip_runtime.h>

#define NN 50000      // nodes
#define NE 800000     // edges
#define NR 20         // relations
#define NB 8          // bases
#define D  128        // hidden dim
#define DO 64         // output dim
#define EPB 32        // edges per block in edge-GEMM

// ---------------------------------------------------------------------------
// ws layout (bytes):
//   [0          ..  4,000,000) cnt    NN*NR int   -- zeroed each call
//   [4,000,000  .. 29,600,000) agg2   NN*D  f32   -- zeroed each call
//   [29,600,000 .. 29,600,128) relcnt 32 int      -- zeroed each call
//   [29,600,128 .. 29,600,256) relcur 32 int      -- (re)written by prefix
//   [29,600,256 .. 29,600,512) reloff 32 int
//   [29,600,512 .. 29,610,752) W0     NR*D  f32
//   [29,610,752 .. 30,921,472) W1     NR*D*D f32
//   [30,921,472 .. 56,521,472) h1     NN*D  f32
//   [56,521,472 .. 59,721,472) eidx   NE int
// ---------------------------------------------------------------------------

// Build W0[r,o] = sum_b wcomp0[r,b]*basis0[b,0,o]
// and   W1[r,i,o] = sum_b wcomp1[r,b]*basis1[b,i,o]
__global__ void k_weights(const float* __restrict__ basis0,
                          const float* __restrict__ wcomp0,
                          const float* __restrict__ basis1,
                          const float* __restrict__ wcomp1,
                          float* __restrict__ W0, float* __restrict__ W1) {
    int idx = blockIdx.x * blockDim.x + threadIdx.x;
    if (idx < NR * D) {
        int r = idx / D, o = idx % D;
        float a = 0.f;
        #pragma unroll
        for (int b = 0; b < NB; b++) a += wcomp0[r * NB + b] * basis0[b * D + o];
        W0[idx] = a;
    }
    for (int j = idx; j < NR * D * D; j += gridDim.x * blockDim.x) {
        int r = j / (D * D), io = j % (D * D);
        float a = 0.f;
        #pragma unroll
        for (int b = 0; b < NB; b++) a += wcomp1[r * NB + b] * basis1[b * D * D + io];
        W1[j] = a;
    }
}

// Per-(dst,rel) edge count histogram + per-relation histogram
__global__ void k_hist(const int* __restrict__ dst, const int* __restrict__ et,
                       int* __restrict__ cnt, int* __restrict__ relcnt) {
    int i = blockIdx.x * blockDim.x + threadIdx.x;
    if (i < NE) {
        atomicAdd(&cnt[dst[i] * NR + et[i]], 1);
        atomicAdd(&relcnt[et[i]], 1);
    }
}

// Exclusive prefix over 20 relations (single thread: trivial)
__global__ void k_prefix(const int* __restrict__ relcnt,
                         int* __restrict__ reloff, int* __restrict__ relcur) {
    if (threadIdx.x == 0 && blockIdx.x == 0) {
        int acc = 0;
        for (int r = 0; r < NR; r++) { reloff[r] = acc; relcur[r] = acc; acc += relcnt[r]; }
        reloff[NR] = acc;
    }
}

// Counting-sort scatter: eidx grouped by relation
__global__ void k_scatter(const int* __restrict__ et, int* __restrict__ relcur,
                          int* __restrict__ eidx) {
    int i = blockIdx.x * blockDim.x + threadIdx.x;
    if (i < NE) {
        int pos = atomicAdd(&relcur[et[i]], 1);
        eidx[pos] = i;
    }
}

// h1[n] = relu(bias0 + sum_r cnt[n,r]*W0[r])   (layer 0 with h = ones[N,1])
__global__ __launch_bounds__(128) void k_h1(const int* __restrict__ cnt,
                                            const float* __restrict__ W0,
                                            const float* __restrict__ bias0,
                                            float* __restrict__ h1) {
    int n = blockIdx.x, t = threadIdx.x;
    __shared__ float cs[NR];
    if (t < NR) cs[t] = (float)cnt[n * NR + t];
    __syncthreads();
    float acc = bias0[t];
    #pragma unroll
    for (int r = 0; r < NR; r++) acc += cs[r] * W0[r * D + t];
    h1[n * D + t] = fmaxf(acc, 0.f);
}

#define FMA4(ACC, A, W) { (ACC).x += (A)*(W).x; (ACC).y += (A)*(W).y; \
                          (ACC).z += (A)*(W).z; (ACC).w += (A)*(W).w; }

// Edge GEMM: per block, 32 same-relation sorted edges:
//   C[32 x 128] = h1[srcs][32 x 128] @ W1[rel][128 x 128], atomic-scatter rows to agg2[dst]
// Thread tiling: 256 threads, each computes 4 edges x 4 outputs.
__global__ __launch_bounds__(256) void k_edge(const int* __restrict__ src,
                                              const int* __restrict__ dst,
                                              const int* __restrict__ eidx,
                                              const int* __restrict__ reloff,
                                              const float* __restrict__ h1,
                                              const float* __restrict__ W1,
                                              float* __restrict__ agg2) {
    int rel = blockIdx.y;
    int begin = reloff[rel], end = reloff[rel + 1];
    int base = begin + blockIdx.x * EPB;
    if (base >= end) return;
    int m = min(EPB, end - base);
    int t = threadIdx.x;

    __shared__ int srcs[EPB], dsts[EPB];
    __shared__ float As[EPB * D];

    if (t < EPB) {
        int s = 0, d = 0;
        if (t < m) { int e = eidx[base + t]; s = src[e]; d = dst[e]; }
        srcs[t] = s; dsts[t] = d;
    }
    __syncthreads();

    float4* As4 = (float4*)As;
    for (int idx = t; idx < EPB * (D / 4); idx += 256) {
        int j = idx / (D / 4), q = idx % (D / 4);
        float4 v = {0.f, 0.f, 0.f, 0.f};
        if (j < m) v = *(const float4*)(h1 + srcs[j] * D + q * 4);
        As4[idx] = v;
    }
    __syncthreads();

    const float* Wg = W1 + rel * D * D;
    int og = t & 31, eg = t >> 5;
    int o0 = og * 4, e0 = eg * 4;

    float4 acc0 = {0,0,0,0}, acc1 = {0,0,0,0}, acc2 = {0,0,0,0}, acc3 = {0,0,0,0};

    for (int k4 = 0; k4 < D / 4; k4++) {
        float4 w0 = *(const float4*)(Wg + (k4 * 4 + 0) * D + o0);
        float4 w1 = *(const float4*)(Wg + (k4 * 4 + 1) * D + o0);
        float4 w2 = *(const float4*)(Wg + (k4 * 4 + 2) * D + o0);
        float4 w3 = *(const float4*)(Wg + (k4 * 4 + 3) * D + o0);
        float4 a;
        a = As4[(e0 + 0) * (D / 4) + k4];
        FMA4(acc0, a.x, w0); FMA4(acc0, a.y, w1); FMA4(acc0, a.z, w2); FMA4(acc0, a.w, w3);
        a = As4[(e0 + 1) * (D / 4) + k4];
        FMA4(acc1, a.x, w0); FMA4(acc1, a.y, w1); FMA4(acc1, a.z, w2); FMA4(acc1, a.w, w3);
        a = As4[(e0 + 2) * (D / 4) + k4];
        FMA4(acc2, a.x, w0); FMA4(acc2, a.y, w1); FMA4(acc2, a.z, w2); FMA4(acc2, a.w, w3);
        a = As4[(e0 + 3) * (D / 4) + k4];
        FMA4(acc3, a.x, w0); FMA4(acc3, a.y, w1); FMA4(acc3, a.z, w2); FMA4(acc3, a.w, w3);
    }

    float4 accs[4] = {acc0, acc1, acc2, acc3};
    #pragma unroll
    for (int j = 0; j < 4; j++) {
        int e = e0 + j;
        if (e < m) {
            float* p = agg2 + dsts[e] * D + o0;
            atomicAdd(p + 0, accs[j].x);
            atomicAdd(p + 1, accs[j].y);
            atomicAdd(p + 2, accs[j].z);
            atomicAdd(p + 3, accs[j].w);
        }
    }
}

// out[n] = relu(agg2[n] + bias1) @ lin_w + lin_b
__global__ __launch_bounds__(64) void k_out(const float* __restrict__ agg2,
                                            const float* __restrict__ bias1,
                                            const float* __restrict__ lin_w,
                                            const float* __restrict__ lin_b,
                                            float* __restrict__ out) {
    int n = blockIdx.x, t = threadIdx.x;
    __shared__ float hs[D];
    hs[t]      = fmaxf(agg2[n * D + t]      + bias1[t],      0.f);
    hs[t + 64] = fmaxf(agg2[n * D + t + 64] + bias1[t + 64], 0.f);
    __syncthreads();
    float acc = lin_b[t];
    #pragma unroll 16
    for (int k = 0; k < D; k++) acc += hs[k] * lin_w[k * DO + t];
    out[n * DO + t] = acc;
}

extern "C" void kernel_launch(void* const* d_in, const int* in_sizes, int n_in,
                              void* d_out, int out_size, void* d_ws, size_t ws_size,
                              hipStream_t stream) {
    const int*   src    = (const int*)d_in[0];
    const int*   dst    = (const int*)d_in[1];
    const int*   et     = (const int*)d_in[2];
    // d_in[3] = num_nodes (scalar) -- compile-time constant NN
    const float* basis0 = (const float*)d_in[4];
    const float* wcomp0 = (const float*)d_in[5];
    const float* bias0  = (const float*)d_in[6];
    const float* basis1 = (const float*)d_in[7];
    const float* wcomp1 = (const float*)d_in[8];
    const float* bias1  = (const float*)d_in[9];
    const float* lin_w  = (const float*)d_in[10];
    const float* lin_b  = (const float*)d_in[11];
    float* out = (float*)d_out;

    char* ws = (char*)d_ws;
    int*   cnt    = (int*)  (ws + 0);
    float* agg2   = (float*)(ws + 4000000);
    int*   relcnt = (int*)  (ws + 29600000);
    int*   relcur = (int*)  (ws + 29600128);
    int*   reloff = (int*)  (ws + 29600256);
    float* W0     = (float*)(ws + 29600512);
    float* W1     = (float*)(ws + 29610752);
    float* h1     = (float*)(ws + 30921472);
    int*   eidx   = (int*)  (ws + 56521472);

    // zero cnt + agg2 + relcnt (+relcur; rewritten by prefix anyway)
    hipMemsetAsync(ws, 0, 29600256, stream);

    k_weights<<<1280, 256, 0, stream>>>(basis0, wcomp0, basis1, wcomp1, W0, W1);
    k_hist<<<(NE + 255) / 256, 256, 0, stream>>>(dst, et, cnt, relcnt);
    k_prefix<<<1, 64, 0, stream>>>(relcnt, reloff, relcur);
    k_scatter<<<(NE + 255) / 256, 256, 0, stream>>>(et, relcur, eidx);
    k_h1<<<NN, 128, 0, stream>>>(cnt, W0, bias0, h1);
    // 4096 batches/relation covers up to 131072 edges of one relation
    // (uniform etype over 20 rels -> ~40000 +/- 200 each; huge margin)
    k_edge<<<dim3(4096, NR), 256, 0, stream>>>(src, dst, eidx, reloff, h1, W1, agg2);
    k_out<<<NN, 64, 0, stream>>>(agg2, bias1, lin_w, lin_b, out);
}

// Round 2
// 472.926 us; speedup vs baseline: 11.3176x; 11.3176x over previous
//
#include <hip/hip_runtime.h>
#include <hip/hip_bf16.h>

#define NN 50000      // nodes
#define NE 800000     // edges
#define NR 20         // relations
#define NB 8          // bases
#define D  128        // hidden dim
#define DO 64         // output dim
#define EPB 64        // edges per block in edge-GEMM

typedef __attribute__((ext_vector_type(8))) short short8;
typedef __attribute__((ext_vector_type(4))) float f32x4;

__device__ inline unsigned short f2bf(float f) {
    __hip_bfloat16 h = __float2bfloat16(f);
    return *reinterpret_cast<unsigned short*>(&h);
}

// ---------------------------------------------------------------------------
// ws layout (bytes):
//   [0          ..  4,000,000) cnt    NN*NR int   -- zeroed each call
//   [4,000,000  .. 29,600,000) agg2   NN*D  f32   -- zeroed each call
//   [29,600,000 .. 29,600,128) relcnt 32 int      -- zeroed each call
//   [29,600,128 .. 29,600,256) relcur 32 int      -- zeroed (rewritten by prefix)
//   [29,600,256 .. 29,600,512) reloff 32 int
//   [29,600,512 .. 29,610,752) W0     NR*D  f32
//   [29,610,752 .. 30,266,112) W1b    NR*16384 bf16 (B-fragment order)
//   [30,266,112 .. 43,066,112) h1b    NN*D  bf16
//   [43,066,112 .. 46,266,112) eidx   NE int
// ---------------------------------------------------------------------------

// W0[r,o] = sum_b wcomp0[r,b]*basis0[b,0,o]    (f32, for exact layer-0)
// W1b in MFMA B-fragment layout, bf16:
//   task = ((rel*4 + kc)*8 + cb)*64 + lane ; elem e in 0..7:
//   value = W1[rel][kc*32 + (lane>>4)*8 + e][cb*16 + (lane&15)]
__global__ __launch_bounds__(256) void k_weights(
        const float* __restrict__ basis0, const float* __restrict__ wcomp0,
        const float* __restrict__ basis1, const float* __restrict__ wcomp1,
        float* __restrict__ W0, unsigned short* __restrict__ W1b) {
    int idx = blockIdx.x * 256 + threadIdx.x;   // 0..40959
    if (idx < NR * D) {
        int r = idx / D, o = idx % D;
        float a = 0.f;
        #pragma unroll
        for (int b = 0; b < NB; b++) a += wcomp0[r * NB + b] * basis0[b * D + o];
        W0[idx] = a;
    }
    if (idx < NR * 4 * 8 * 64) {
        int lane = idx & 63;
        int cb   = (idx >> 6) & 7;
        int kc   = (idx >> 9) & 3;
        int rel  = idx >> 11;
        float wc[NB];
        #pragma unroll
        for (int b = 0; b < NB; b++) wc[b] = wcomp1[rel * NB + b];
        int o  = cb * 16 + (lane & 15);
        int i0 = kc * 32 + (lane >> 4) * 8;
        short8 v;
        #pragma unroll
        for (int e = 0; e < 8; e++) {
            int i = i0 + e;
            float a = 0.f;
            #pragma unroll
            for (int b = 0; b < NB; b++) a += wc[b] * basis1[(b * D + i) * D + o];
            v[e] = (short)f2bf(a);
        }
        *((short8*)W1b + idx) = v;
    }
}

// Per-(dst,rel) histogram (scattered atomics, 1M addrs: fine) +
// per-relation histogram via block-LDS aggregation (782 atomics/address).
__global__ __launch_bounds__(1024) void k_hist(
        const int* __restrict__ dst, const int* __restrict__ et,
        int* __restrict__ cnt, int* __restrict__ relcnt) {
    __shared__ int lh[NR];
    int t = threadIdx.x;
    if (t < NR) lh[t] = 0;
    __syncthreads();
    int i = blockIdx.x * 1024 + t;
    if (i < NE) {
        atomicAdd(&cnt[dst[i] * NR + et[i]], 1);
        atomicAdd(&lh[et[i]], 1);
    }
    __syncthreads();
    if (t < NR) atomicAdd(&relcnt[t], lh[t]);
}

__global__ void k_prefix(const int* __restrict__ relcnt,
                         int* __restrict__ reloff, int* __restrict__ relcur) {
    if (threadIdx.x == 0 && blockIdx.x == 0) {
        int acc = 0;
        for (int r = 0; r < NR; r++) { reloff[r] = acc; relcur[r] = acc; acc += relcnt[r]; }
        reloff[NR] = acc;
    }
}

// Counting-sort scatter, block-aggregated: one global atomic per (rel,block).
// Order within a relation is arbitrary -- k_edge is symmetric in group order.
__global__ __launch_bounds__(1024) void k_scatter(
        const int* __restrict__ et, int* __restrict__ relcur,
        int* __restrict__ eidx) {
    __shared__ int lh[NR], lbase[NR];
    int t = threadIdx.x;
    if (t < NR) lh[t] = 0;
    __syncthreads();
    int i = blockIdx.x * 1024 + t;
    int r = 0, rk = 0;
    bool ok = (i < NE);
    if (ok) { r = et[i]; rk = atomicAdd(&lh[r], 1); }
    __syncthreads();
    if (t < NR) lbase[t] = atomicAdd(&relcur[t], lh[t]);
    __syncthreads();
    if (ok) eidx[lbase[r] + rk] = i;
}

// h1b[n] = bf16(relu(bias0 + sum_r cnt[n,r]*W0[r]))   (layer 0, h = ones)
__global__ __launch_bounds__(128) void k_h1(const int* __restrict__ cnt,
                                            const float* __restrict__ W0,
                                            const float* __restrict__ bias0,
                                            unsigned short* __restrict__ h1b) {
    int n = blockIdx.x, t = threadIdx.x;
    __shared__ float cs[NR];
    if (t < NR) cs[t] = (float)cnt[n * NR + t];
    __syncthreads();
    float acc = bias0[t];
    #pragma unroll
    for (int r = 0; r < NR; r++) acc += cs[r] * W0[r * D + t];
    h1b[n * D + t] = f2bf(fmaxf(acc, 0.f));
}

// Edge GEMM (bf16 MFMA): per block, 64 same-relation edges:
//   C[64 x 128] = h1b[srcs] @ W1[rel], atomic-scatter rows to agg2[dst].
// 4 waves; wave w computes rows w*16..w*16+15 over all 128 cols.
// A staged in LDS, XOR-swizzled (chunk ^= row&7) -> conflict-free ds_read_b128.
// B read from global in pre-swizzled fragment order (16B/lane, coalesced).
__global__ __launch_bounds__(256) void k_edge(
        const int* __restrict__ src, const int* __restrict__ dst,
        const int* __restrict__ eidx, const int* __restrict__ reloff,
        const unsigned short* __restrict__ h1b,
        const unsigned short* __restrict__ W1b,
        float* __restrict__ agg2) {
    int rel = blockIdx.y;
    int begin = reloff[rel], end = reloff[rel + 1];
    int base = begin + blockIdx.x * EPB;
    if (base >= end) return;
    int m = min(EPB, end - base);
    int t = threadIdx.x;

    __shared__ int srcs[EPB], dsts[EPB];
    __shared__ short As[EPB * D];   // [64 rows][16 chunks of 8 bf16], swizzled

    if (t < EPB) {
        int s = 0, d = 0;
        if (t < m) { int e = eidx[base + t]; s = src[e]; d = dst[e]; }
        srcs[t] = s; dsts[t] = d;
    }
    __syncthreads();

    short8* As8 = (short8*)As;
    for (int idx = t; idx < EPB * 16; idx += 256) {
        int row = idx >> 4, c = idx & 15;
        short8 v = {0, 0, 0, 0, 0, 0, 0, 0};
        if (row < m) v = *(const short8*)(h1b + srcs[row] * D + c * 8);
        As8[row * 16 + (c ^ (row & 7))] = v;
    }
    __syncthreads();

    int wave = t >> 6, lane = t & 63;
    int row = lane & 15, g = lane >> 4;

    f32x4 acc[8];
    #pragma unroll
    for (int cb = 0; cb < 8; cb++) acc[cb] = (f32x4){0.f, 0.f, 0.f, 0.f};

    const short8* Wv = (const short8*)W1b + rel * 4 * 8 * 64;
    int arow = wave * 16 + row;

    #pragma unroll
    for (int kc = 0; kc < 4; kc++) {
        int c = kc * 4 + g;
        short8 a = As8[arow * 16 + (c ^ (row & 7))];
        #pragma unroll
        for (int cb = 0; cb < 8; cb++) {
            short8 b = Wv[(kc * 8 + cb) * 64 + lane];
            acc[cb] = __builtin_amdgcn_mfma_f32_16x16x32_bf16(a, b, acc[cb], 0, 0, 0);
        }
    }

    // C/D layout: col = lane&15, row_in_tile = (lane>>4)*4 + reg  [m89 verified]
    #pragma unroll
    for (int cb = 0; cb < 8; cb++) {
        #pragma unroll
        for (int reg = 0; reg < 4; reg++) {
            int er = wave * 16 + g * 4 + reg;
            if (er < m) {
                atomicAdd(&agg2[dsts[er] * D + cb * 16 + row], acc[cb][reg]);
            }
        }
    }
}

// out[n] = relu(agg2[n] + bias1) @ lin_w + lin_b   (exact f32)
__global__ __launch_bounds__(64) void k_out(const float* __restrict__ agg2,
                                            const float* __restrict__ bias1,
                                            const float* __restrict__ lin_w,
                                            const float* __restrict__ lin_b,
                                            float* __restrict__ out) {
    int n = blockIdx.x, t = threadIdx.x;
    __shared__ float hs[D];
    hs[t]      = fmaxf(agg2[n * D + t]      + bias1[t],      0.f);
    hs[t + 64] = fmaxf(agg2[n * D + t + 64] + bias1[t + 64], 0.f);
    __syncthreads();
    float acc = lin_b[t];
    #pragma unroll 16
    for (int k = 0; k < D; k++) acc += hs[k] * lin_w[k * DO + t];
    out[n * DO + t] = acc;
}

extern "C" void kernel_launch(void* const* d_in, const int* in_sizes, int n_in,
                              void* d_out, int out_size, void* d_ws, size_t ws_size,
                              hipStream_t stream) {
    const int*   src    = (const int*)d_in[0];
    const int*   dst    = (const int*)d_in[1];
    const int*   et     = (const int*)d_in[2];
    const float* basis0 = (const float*)d_in[4];
    const float* wcomp0 = (const float*)d_in[5];
    const float* bias0  = (const float*)d_in[6];
    const float* basis1 = (const float*)d_in[7];
    const float* wcomp1 = (const float*)d_in[8];
    const float* bias1  = (const float*)d_in[9];
    const float* lin_w  = (const float*)d_in[10];
    const float* lin_b  = (const float*)d_in[11];
    float* out = (float*)d_out;

    char* ws = (char*)d_ws;
    int*            cnt    = (int*)           (ws + 0);
    float*          agg2   = (float*)         (ws + 4000000);
    int*            relcnt = (int*)           (ws + 29600000);
    int*            relcur = (int*)           (ws + 29600128);
    int*            reloff = (int*)           (ws + 29600256);
    float*          W0     = (float*)         (ws + 29600512);
    unsigned short* W1b    = (unsigned short*)(ws + 29610752);
    unsigned short* h1b    = (unsigned short*)(ws + 30266112);
    int*            eidx   = (int*)           (ws + 43066112);

    // zero cnt + agg2 + relcnt + relcur
    hipMemsetAsync(ws, 0, 29600256, stream);

    k_weights<<<160, 256, 0, stream>>>(basis0, wcomp0, basis1, wcomp1, W0, W1b);
    k_hist<<<(NE + 1023) / 1024, 1024, 0, stream>>>(dst, et, cnt, relcnt);
    k_prefix<<<1, 64, 0, stream>>>(relcnt, reloff, relcur);
    k_scatter<<<(NE + 1023) / 1024, 1024, 0, stream>>>(et, relcur, eidx);
    k_h1<<<NN, 128, 0, stream>>>(cnt, W0, bias0, h1b);
    // 1024 blocks/relation covers up to 65536 edges of one relation
    // (uniform etype -> ~40000 +/- 200 each; 5-sigma margin is ~41000)
    k_edge<<<dim3(1024, NR), 256, 0, stream>>>(src, dst, eidx, reloff, h1b, W1b, agg2);
    k_out<<<NN, 64, 0, stream>>>(agg2, bias1, lin_w, lin_b, out);
}